// Round 7
// baseline (306.781 us; speedup 1.0000x reference)
//
#include <hip/hip_runtime.h>
#include <math.h>

typedef float f4 __attribute__((ext_vector_type(4)));
typedef float f32x4 __attribute__((ext_vector_type(4)));
typedef _Float16 h4 __attribute__((ext_vector_type(4)));
typedef _Float16 h8 __attribute__((ext_vector_type(8)));

#define NB 1024
#define NR 10
#define NL 512
#define NM (NB*NR)      // 10240 rows
#define NK (2*NL)       // 1024  K-dim

#define BIMG_OFF   131072ull
#define BIMG_EMBED 4194304ull                       // 4 MB per embed (B image)
#define WS_NEED    (BIMG_OFF + 2ull*BIMG_EMBED)     // ~8.5 MB

#define SCALE_A 16.0f
#define SCALE_B 512.0f
#define INV_SCALE (1.0f/8192.0f)

// async global -> LDS, 16B per lane (dest = wave-uniform base + lane*16)
__device__ __forceinline__ void gl_lds16(const void* g, void* s) {
    __builtin_amdgcn_global_load_lds(
        (const __attribute__((address_space(1))) unsigned int*)g,
        (__attribute__((address_space(3))) unsigned int*)s, 16, 0, 0);
}

// ===================== prep: weight split + vcalc + zero ====================
// blocks [0,1024)      : weight split (nh 8, ks 32, mi 4)
// blocks [1024,2049)   : vcalc        (o 0..1024)
// blocks [2049,2069)   : zero t_h/t_q (20 blocks x 1024 floats)
__global__ __launch_bounds__(256) void k_prep(
    const float* __restrict__ Wy_h, const float* __restrict__ Wg_h,
    const float* __restrict__ Wy_q, const float* __restrict__ Wg_q,
    const float* __restrict__ W1, const float* __restrict__ b1,
    const float* __restrict__ W2, const float* __restrict__ b2,
    char* __restrict__ Bimg,
    float* __restrict__ vh, float* __restrict__ vq, float* __restrict__ cc,
    float* __restrict__ tzero)
{
    __shared__ float Ws[32][68];
    __shared__ float red[4];
    const int bid = blockIdx.x;
    const int t = threadIdx.x;

    if (bid < 1024) {
        // ---- weight pre-split: [nt][ks][s(2)][nf(8)][lane(64)][e(8)] f16
        const int nh = bid % 8, ks = (bid / 8) % 32, mi = bid / 256;
        const float* W = (mi==0) ? Wy_h : (mi==1) ? Wg_h : (mi==2) ? Wy_q : Wg_q;
        const int emb = mi >> 1, nfb = (mi & 1) * 4;
        const int kl = t >> 4, nl4 = (t & 15) * 4;
        #pragma unroll
        for (int i = 0; i < 2; ++i) {
            f4 wv = *(const f4*)(W + (size_t)(ks*32 + kl + 16*i)*NL + nh*64 + nl4);
            *(f4*)&Ws[kl + 16*i][nl4] = wv;
        }
        __syncthreads();
        const int kg = t >> 6, nl = t & 63;
        h8 hi, lo;
        #pragma unroll
        for (int e8 = 0; e8 < 8; ++e8) {
            float x = Ws[kg*8 + e8][nl] * SCALE_B;
            _Float16 h = (_Float16)x;
            hi[e8] = h;
            lo[e8] = (_Float16)(x - (float)h);
        }
        const int nf  = nfb + (nl >> 4);
        const int l16 = (nl & 15) + 16*kg;
        char* p = Bimg + (size_t)emb*BIMG_EMBED
                + ((size_t)(nh*32 + ks)*2)*8192 + nf*1024 + l16*16;
        *(h8*)p = hi;
        *(h8*)(p + 8192) = lo;
    } else if (bid < 2049) {
        // ---- v_h = W1[:L]@W2, v_q = W1[L:]@W2, c = b1.W2 + b2
        const int o = bid - 1024;
        const float* row = (o < 1024) ? (W1 + (size_t)o*NL) : b1;
        float s = fmaf(row[t], W2[t], row[t+256]*W2[t+256]);
        #pragma unroll
        for (int d = 1; d < 64; d <<= 1) s += __shfl_xor(s, d);
        if ((t & 63) == 0) red[t >> 6] = s;
        __syncthreads();
        if (t == 0) {
            float tot = red[0] + red[1] + red[2] + red[3];
            if (o < 512) vh[o] = tot;
            else if (o < 1024) vq[o-512] = tot;
            else cc[0] = tot + b2[0];
        }
    } else {
        // ---- zero t_h/t_q (2*NM = 20480 floats)
        const int zb = bid - 2049;
        f4 zz = {0.f, 0.f, 0.f, 0.f};
        *(f4*)(tzero + (size_t)zb*1024 + t*4) = zz;
    }
}

// ===================== main embed: pipelined, reg-staged A ==================
// Block tile: 128 rows x (64 y-cols + 64 g-cols). 4 waves = 2(row) x 2(col).
// A: raw f32 global -> regs (2 steps ahead) -> split -> ds_write next buffer.
// B: pre-split image via global_load_lds. Counted vmcnt, raw barriers.
__global__ __launch_bounds__(256, 2) void k_embed_mfma4(
    const float* __restrict__ hist, const float* __restrict__ ques,
    const char* __restrict__ Bimg,
    const float* __restrict__ by_h, const float* __restrict__ bg_h,
    const float* __restrict__ by_q, const float* __restrict__ bg_q,
    const float* __restrict__ vv, float* __restrict__ tout)
{
    const int z = blockIdx.z, nt = blockIdx.y, rb = blockIdx.x;
    const float* X  = z ? ques : hist;
    const float* by = z ? by_q : by_h;
    const float* bg = z ? bg_q : bg_h;
    const float* v  = vv + z*NL;
    float* tptr = tout + (size_t)z*NM;
    const char* Bt = Bimg + (size_t)z*BIMG_EMBED + (size_t)nt*32*16384;

    __shared__ char smem[65536];          // 2 buffers x (16K A + 16K B)

    const int t = threadIdx.x;
    const int l = t & 63, w = t >> 6;
    const int wr = w >> 1, wc = w & 1;

    // A staging: thread t covers m-slots (t>>6) and (t>>6)+4, lane t&63,
    // k-chunk ((t>>4)&3)*8 .. +7  (matches frag layout [s][m][lane][e])
    const int am0 = t >> 6;
    const float* src1 = X + (size_t)(rb*128 + am0*16 + (t & 15))*NK + ((t >> 4) & 3)*8;
    const float* src2 = src1 + (size_t)64*NK;
    const int aw1 = am0*1024 + (t & 63)*16;     // + s*8192 + buf*32768
    const int aw2 = aw1 + 4096;

    f4 ar0, ar1, ar2, ar3;                      // A(k) in flight (one step)
    auto loadA = [&](int ksrc) {
        const float* p1 = src1 + ksrc*32;
        const float* p2 = src2 + ksrc*32;
        ar0 = *(const f4*)p1; ar1 = *(const f4*)(p1 + 4);
        ar2 = *(const f4*)p2; ar3 = *(const f4*)(p2 + 4);
    };
    auto splitA = [&](char* base) {              // 4x ds_write_b128, contiguous
        h8 hi1, lo1, hi2, lo2;
        #pragma unroll
        for (int j = 0; j < 4; ++j) {
            float x0 = ar0[j]*SCALE_A; _Float16 h0 = (_Float16)x0;
            hi1[j] = h0;   lo1[j] = (_Float16)(x0 - (float)h0);
            float x1 = ar1[j]*SCALE_A; _Float16 h1 = (_Float16)x1;
            hi1[4+j] = h1; lo1[4+j] = (_Float16)(x1 - (float)h1);
            float x2 = ar2[j]*SCALE_A; _Float16 h2 = (_Float16)x2;
            hi2[j] = h2;   lo2[j] = (_Float16)(x2 - (float)h2);
            float x3 = ar3[j]*SCALE_A; _Float16 h3 = (_Float16)x3;
            hi2[4+j] = h3; lo2[4+j] = (_Float16)(x3 - (float)h3);
        }
        *(h8*)(base + aw1) = hi1;  *(h8*)(base + 8192 + aw1) = lo1;
        *(h8*)(base + aw2) = hi2;  *(h8*)(base + 8192 + aw2) = lo2;
    };
    auto stageB = [&](int buf, int ksrc) {       // 4x gl_lds16 per wave
        const char* gb = Bt + (size_t)ksrc*16384 + w*4096 + l*16;
        char* db = smem + buf*32768 + 16384 + w*4096;
        #pragma unroll
        for (int j = 0; j < 4; ++j) gl_lds16(gb + j*1024, db + j*1024);
    };

    f32x4 acc[4][4];
    #pragma unroll
    for (int m = 0; m < 4; ++m)
      #pragma unroll
      for (int n = 0; n < 4; ++n) { f32x4 zz = {0.f,0.f,0.f,0.f}; acc[m][n] = zz; }

    // ---- prologue: A(0) split into buf0; A(1) into regs; B(0),B(1) in flight
    loadA(0);
    splitA(smem);                 // compiler waits on ar regs
    loadA(1);
    stageB(0, 0);
    stageB(1, 1);
    asm volatile("s_waitcnt lgkmcnt(0)" ::: "memory");   // my A(0) writes drained
    asm volatile("s_waitcnt vmcnt(4)" ::: "memory");     // B(0) landed (B(1) flies)
    __builtin_amdgcn_s_barrier();

    #pragma unroll 2
    for (int ks = 0; ks < 32; ++ks) {
        const int cur = ks & 1, nxt = cur ^ 1;
        const char* sA = smem + cur*32768;
        const char* sB = sA + 16384;

        // step1: split A(ks+1) -> buf[nxt] (safe since last barrier)
        if (ks < 31) splitA(smem + nxt*32768);

        // step2: fragment reads of step ks
        h8 av[4][2], bv[4][2];
        #pragma unroll
        for (int m = 0; m < 4; ++m)
          #pragma unroll
          for (int s = 0; s < 2; ++s)
            av[m][s] = *(const h8*)(sA + s*8192 + (wr*4 + m)*1024 + l*16);
        #pragma unroll
        for (int fn = 0; fn < 4; ++fn) {
            const int nf = (fn < 2) ? (wc*2 + fn) : (4 + wc*2 + (fn - 2));
            #pragma unroll
            for (int s = 0; s < 2; ++s)
                bv[fn][s] = *(const h8*)(sB + s*8192 + nf*1024 + l*16);
        }

        // step3: A(ks+2) -> regs
        if (ks < 30) loadA(ks + 2);

        // step4: my reads+writes drained -> barrier
        asm volatile("s_waitcnt lgkmcnt(0)" ::: "memory");
        __builtin_amdgcn_sched_barrier(0);
        __builtin_amdgcn_s_barrier();

        // step5: B(ks+2) -> buf[cur] (all waves done reading it)
        if (ks < 30) stageB(cur, ks + 2);

        // step6: MFMA cluster
        __builtin_amdgcn_s_setprio(1);
        #pragma unroll
        for (int m = 0; m < 4; ++m)
          #pragma unroll
          for (int fn = 0; fn < 4; ++fn) {
            acc[m][fn] = __builtin_amdgcn_mfma_f32_16x16x32_f16(av[m][0], bv[fn][0], acc[m][fn], 0, 0, 0);
            acc[m][fn] = __builtin_amdgcn_mfma_f32_16x16x32_f16(av[m][0], bv[fn][1], acc[m][fn], 0, 0, 0);
            acc[m][fn] = __builtin_amdgcn_mfma_f32_16x16x32_f16(av[m][1], bv[fn][0], acc[m][fn], 0, 0, 0);
          }
        __builtin_amdgcn_s_setprio(0);

        // step7: counted wait -> B(ks+1) resident for next iter
        if (ks < 30)       asm volatile("s_waitcnt vmcnt(8)" ::: "memory");
        else if (ks == 30) asm volatile("s_waitcnt vmcnt(0)" ::: "memory");
        if (ks < 31) __builtin_amdgcn_s_barrier();
    }

    // ---- epilogue: unscale, bias, tanh*sigmoid, dot v, row-reduce, atomic
    const int coll = l & 15, rg = l >> 4;
    #pragma unroll
    for (int m = 0; m < 4; ++m) {
      #pragma unroll
      for (int r = 0; r < 4; ++r) {
        float ps = 0.0f;
        #pragma unroll
        for (int n = 0; n < 2; ++n) {
            const int c = nt*64 + wc*32 + n*16 + coll;
            float y = acc[m][n  ][r]*INV_SCALE + by[c];
            float g = acc[m][n+2][r]*INV_SCALE + bg[c];
            ps += v[c] * (tanhf(y) * (1.0f/(1.0f + expf(-g))));
        }
        ps += __shfl_xor(ps, 1);
        ps += __shfl_xor(ps, 2);
        ps += __shfl_xor(ps, 4);
        ps += __shfl_xor(ps, 8);
        if (coll == 0)
            atomicAdd(&tptr[rb*128 + wr*64 + m*16 + rg*4 + r], ps);
      }
    }
}

// ---------------- fallback f32 path (verified round 1) ----------------------
__global__ __launch_bounds__(256) void k_vcalc2(const float* __restrict__ W1,
    const float* __restrict__ b1, const float* __restrict__ W2,
    const float* __restrict__ b2, float* __restrict__ vh,
    float* __restrict__ vq, float* __restrict__ cc)
{
    const int o = blockIdx.x;
    const float* row = (o < 1024) ? (W1 + (size_t)o*NL) : b1;
    const int t = threadIdx.x;
    float s = fmaf(row[t], W2[t], row[t+256]*W2[t+256]);
    #pragma unroll
    for (int d = 1; d < 64; d <<= 1) s += __shfl_xor(s, d);
    __shared__ float red[4];
    if ((t & 63) == 0) red[t >> 6] = s;
    __syncthreads();
    if (t == 0) {
        float tot = red[0] + red[1] + red[2] + red[3];
        if (o < 512) vh[o] = tot;
        else if (o < 1024) vq[o-512] = tot;
        else cc[0] = tot + b2[0];
    }
}

__global__ __launch_bounds__(256) void k_embed(const float* __restrict__ X,
    const float* __restrict__ Wy, const float* __restrict__ by,
    const float* __restrict__ Wg, const float* __restrict__ bg,
    const float* __restrict__ v, float* __restrict__ tout)
{
    __shared__ float As[32][68];
    __shared__ float Bys[32][64];
    __shared__ float Bgs[32][64];
    const int tid  = threadIdx.x;
    const int row0 = blockIdx.x * 64;
    const int c0   = blockIdx.y * 64;
    const int tx = tid & 15, ty = tid >> 4;
    float accy[4][4] = {};
    float accg[4][4] = {};
    const int arow = tid >> 3;
    const int ak   = (tid & 7) << 2;
    const int bk   = tid >> 4;
    const int bc   = (tid & 15) << 2;
    const float* Xp0 = X + (size_t)(row0 + arow)*NK + ak;
    const float* Xp1 = Xp0 + (size_t)32*NK;
    for (int k0 = 0; k0 < NK; k0 += 32) {
        f4 a0 = *(const f4*)(Xp0 + k0);
        f4 a1 = *(const f4*)(Xp1 + k0);
        f4 y0 = *(const f4*)&Wy[(size_t)(k0+bk   )*NL + c0 + bc];
        f4 y1 = *(const f4*)&Wy[(size_t)(k0+bk+16)*NL + c0 + bc];
        f4 g0 = *(const f4*)&Wg[(size_t)(k0+bk   )*NL + c0 + bc];
        f4 g1 = *(const f4*)&Wg[(size_t)(k0+bk+16)*NL + c0 + bc];
        #pragma unroll
        for (int j = 0; j < 4; ++j) {
            As[ak+j][arow]      = a0[j];
            As[ak+j][arow + 32] = a1[j];
        }
        *(f4*)&Bys[bk   ][bc] = y0;
        *(f4*)&Bys[bk+16][bc] = y1;
        *(f4*)&Bgs[bk   ][bc] = g0;
        *(f4*)&Bgs[bk+16][bc] = g1;
        __syncthreads();
        #pragma unroll
        for (int kk = 0; kk < 32; ++kk) {
            f4 a   = *(const f4*)&As [kk][ty<<2];
            f4 byv = *(const f4*)&Bys[kk][tx<<2];
            f4 bgv = *(const f4*)&Bgs[kk][tx<<2];
            #pragma unroll
            for (int rr = 0; rr < 4; ++rr)
                #pragma unroll
                for (int cc2 = 0; cc2 < 4; ++cc2) {
                    accy[rr][cc2] = fmaf(a[rr], byv[cc2], accy[rr][cc2]);
                    accg[rr][cc2] = fmaf(a[rr], bgv[cc2], accg[rr][cc2]);
                }
        }
        __syncthreads();
    }
    float rowsum[4] = {0.f, 0.f, 0.f, 0.f};
    #pragma unroll
    for (int rr = 0; rr < 4; ++rr)
        #pragma unroll
        for (int cc2 = 0; cc2 < 4; ++cc2) {
            int c = c0 + (tx<<2) + cc2;
            float xy = accy[rr][cc2] + by[c];
            float xg = accg[rr][cc2] + bg[c];
            float hv = tanhf(xy) * (1.0f / (1.0f + expf(-xg)));
            rowsum[rr] += v[c] * hv;
        }
    float* red = &As[0][0];
    #pragma unroll
    for (int rr = 0; rr < 4; ++rr) red[(ty*4 + rr)*16 + tx] = rowsum[rr];
    __syncthreads();
    if (tid < 64) {
        float s = 0.0f;
        #pragma unroll
        for (int t2 = 0; t2 < 16; ++t2) s += red[tid*16 + t2];
        atomicAdd(&tout[row0 + tid], s);
    }
}

// ---------------- logits -> masked Gumbel argmax -> one-hot -----------------
__global__ __launch_bounds__(256) void k_final(const float* __restrict__ th,
    const float* __restrict__ tq, const float* __restrict__ cc,
    const float* __restrict__ noise, const float* __restrict__ Wa,
    const float* __restrict__ ba, float* __restrict__ out)
{
    int idx = blockIdx.x*256 + threadIdx.x;   // = b*NR + i
    if (idx >= NM) return;
    int b = idx / NR, i = idx % NR;
    float wa0 = Wa[0], wa1 = Wa[1], bav = ba[0], c = cc[0];
    float ti = tq[idx];
    const float EPS = 1e-10f;
    float best = -3.0e38f; int am = 0;
    for (int j = 0; j < NR; ++j) {
        float zz;
        if (j <= i) {
            float n = noise[idx*NR + j];
            float g = -logf(EPS - logf(n + EPS));
            float score = ti + th[b*NR + j] + c;
            zz = score*wa0 + (float)(i - j + 1)*wa1 + bav + g;
        } else {
            zz = -1.0e9f;
        }
        if (zz > best) { best = zz; am = j; }
    }
    #pragma unroll
    for (int j = 0; j < NR; ++j) out[idx*NR + j] = (j == am) ? 1.0f : 0.0f;
}

extern "C" void kernel_launch(void* const* d_in, const int* in_sizes, int n_in,
                              void* d_out, int out_size, void* d_ws, size_t ws_size,
                              hipStream_t stream) {
    (void)in_sizes; (void)n_in; (void)out_size;
    const float* hist  = (const float*)d_in[0];
    const float* ques  = (const float*)d_in[1];
    const float* noise = (const float*)d_in[2];
    const float* Wy_h  = (const float*)d_in[3];
    const float* by_h  = (const float*)d_in[4];
    const float* Wg_h  = (const float*)d_in[5];
    const float* bg_h  = (const float*)d_in[6];
    const float* Wy_q  = (const float*)d_in[7];
    const float* by_q  = (const float*)d_in[8];
    const float* Wg_q  = (const float*)d_in[9];
    const float* bg_q  = (const float*)d_in[10];
    const float* W1    = (const float*)d_in[11];
    const float* b1    = (const float*)d_in[12];
    const float* W2    = (const float*)d_in[13];
    const float* b2    = (const float*)d_in[14];
    const float* Wa    = (const float*)d_in[15];
    const float* ba    = (const float*)d_in[16];
    float* out = (float*)d_out;

    float* ws     = (float*)d_ws;
    float* t_h    = ws;                 // [10240]
    float* t_q    = ws + NM;            // [10240]
    float* v_h    = ws + 2*NM;          // [512]
    float* v_q    = v_h + NL;           // [512]
    float* cconst = v_q + NL;           // [1]

    if (ws_size >= WS_NEED) {
        char* Bimg = (char*)d_ws + BIMG_OFF;
        k_prep<<<2069, 256, 0, stream>>>(Wy_h, Wg_h, Wy_q, Wg_q,
            W1, b1, W2, b2, Bimg, v_h, v_q, cconst, t_h);
        k_embed_mfma4<<<dim3(80, 8, 2), 256, 0, stream>>>(hist, ques, Bimg,
            by_h, bg_h, by_q, bg_q, v_h, t_h);
    } else {
        hipMemsetAsync(t_h, 0, 2*NM*sizeof(float), stream);
        k_vcalc2<<<1025, 256, 0, stream>>>(W1, b1, W2, b2, v_h, v_q, cconst);
        dim3 g(NM/64, NL/64);
        k_embed<<<g, 256, 0, stream>>>(hist, Wy_h, by_h, Wg_h, bg_h, v_h, t_h);
        k_embed<<<g, 256, 0, stream>>>(ques, Wy_q, by_q, Wg_q, bg_q, v_q, t_q);
    }
    k_final<<<(NM + 255)/256, 256, 0, stream>>>(t_h, t_q, cconst, noise, Wa, ba, out);
}